// Round 11
// baseline (754.838 us; speedup 1.0000x reference)
//
#include <hip/hip_runtime.h>
#include <math.h>

// B=64, I=K=2048, H=N=2048, T=128.  m = b*128 + t (M=8192).
// Numerics contract (VALIDATED GREEN): Eigen gebp kc=320 K-panels; per C
// element an ascending-k FMA chain within each 320-panel (register
// accumulator), panels combined by UNFUSED f32 adds (beta=0 first).
// Spikes are EXACT 0.0f/1.0f, so fma(1,b,acc)=__fadd_rn(acc,b) and
// fma(0,b,acc)=acc bit-for-bit -> skipping zero-spike terms is bit-exact.
// w_eff = __fmul_rn(weight, strength) rounded once. Scan: f32 state,
// unfused mul/add; exact batch mean via ballot/popcount; correctly-rounded
// expf via (float)exp((double)quotient).
//
// R11 = R10 with ONE change: the 8 stride-64-word ds_read_b32 per active k
// are replaced by 4 inline-asm ds_read2st64_b32 (offsets 8*kk+j in 256-B
// units, <=63 fits the 8-bit field; 64 consecutive words per sub-pass ->
// 2/bank free). Theory: compiler never merged the b32 pairs, leaving the
// kernel LDS-issue-bound at 8x5.8 cyc/active-k (~361us/CU). Per rule #18,
// a single s_waitcnt lgkmcnt(0) + sched_barrier(0) fences the reads before
// the adds. Same words -> same bf[j] chain positions -> bit-identical.

__device__ __forceinline__ void async_copy16(const float* g, float* l) {
    __builtin_amdgcn_global_load_lds(
        (const __attribute__((address_space(1))) void*)g,
        (__attribute__((address_space(3))) void*)l, 16, 0, 0);
}

// weff[i][hl] = __fmul_rn(weight[i][h_base+hl], strength[i][h_base+hl])
__global__ __launch_bounds__(256) void weff_kernel(
    const float* __restrict__ weight, const float* __restrict__ strength,
    float* __restrict__ weff, int h_base, int Hc)
{
    const int i = blockIdx.x;  // input row 0..2047
    const float* wr = weight   + (size_t)i * 2048 + h_base;
    const float* sr = strength + (size_t)i * 2048 + h_base;
    float* dr = weff + (size_t)i * Hc;
    for (int c = threadIdx.x * 4; c < Hc; c += 1024) {
        float4 wv = *(const float4*)&wr[c];
        float4 sv = *(const float4*)&sr[c];
        float4 o;
        o.x = __fmul_rn(wv.x, sv.x);
        o.y = __fmul_rn(wv.y, sv.y);
        o.z = __fmul_rn(wv.z, sv.z);
        o.w = __fmul_rn(wv.w, sv.w);
        *(float4*)&dr[c] = o;
    }
}

// bitsT[b][tbyte][k]: bit r = (spikes[b][k][8*tbyte+r] != 0). One wave per
// (b,k): two ballots over 128 t, lanes 0..15 each emit one byte.
__global__ __launch_bounds__(256) void bits_kernel(
    const float* __restrict__ spikes, unsigned char* __restrict__ bitsT)
{
    const int tid  = threadIdx.x;
    const int w    = tid >> 6;
    const int lane = tid & 63;
    const int wid  = blockIdx.x * 4 + w;     // b*2048 + k
    const int b    = wid >> 11;
    const int k    = wid & 2047;
    const float2 v = *(const float2*)&spikes[((size_t)b * 2048 + k) * 128 + 2 * lane];
    const unsigned long long m0 = __ballot(v.x != 0.0f);  // bit l -> t=2l
    const unsigned long long m1 = __ballot(v.y != 0.0f);  // bit l -> t=2l+1
    if (lane < 16) {
        unsigned byte = 0;
#pragma unroll
        for (int q = 0; q < 4; q++) {
            byte |= (unsigned)((m0 >> (4 * lane + q)) & 1ull) << (2 * q);
            byte |= (unsigned)((m1 >> (4 * lane + q)) & 1ull) << (2 * q + 1);
        }
        bitsT[((size_t)b * 16 + lane) * 2048 + k] = (unsigned char)byte;
    }
}

union ShU {
    float Wl[2][8][512];    // 32 KiB: double-buffered weff k-tile (8 k-rows)
    float Cl[16][517];      // 33 KiB: epilogue transpose, 16 m-rows per pass
};

__global__ __launch_bounds__(256, 3) void gemm_kernel(
    const float* __restrict__ weff,          // [2048][Hc]
    const unsigned char* __restrict__ bits,  // [64][16][2048]
    float* __restrict__ Ct,                  // [Hc][M=8192]
    int Hc)
{
    __shared__ ShU sh;

    const int tid  = threadIdx.x;
    const int w    = tid >> 6;          // wave 0..3
    const int lane = tid & 63;
    const int h0   = blockIdx.x * 512;  // chunk-local h-tile
    const int mg   = blockIdx.y;        // 0..255: b = mg>>2, t-quarter = mg&3
    const int b    = mg >> 2;
    const int tq   = mg & 3;
    const int m0g  = b * 128 + tq * 32; // block's first m (32 m per block)
    const int wbyte = (tq << 2) + w;    // wave's t-byte (8 m-rows)

    float acc[8][8];   // acc[r][j]: m-row r, h = h0 + 64*j + lane
    float tot[8][8];   // running unfused panel total
#pragma unroll
    for (int r = 0; r < 8; r++)
#pragma unroll
        for (int j = 0; j < 8; j++) { acc[r][j] = 0.0f; tot[r][j] = 0.0f; }

    const unsigned char* bp = bits + (((size_t)b * 16 + wbyte) << 11);

    // Stage k-tile kt (8 rows x 512 cols = 16 KiB) into buffer buf.
    // Wave w covers rows 2w, 2w+1; each row = 2 KiB as 2 DMA halves.
    auto stageW = [&](int buf, int kt) {
        const int k0 = kt << 3;
        const int r  = w << 1;
#pragma unroll
        for (int i = 0; i < 2; i++) {
            const float* src = &weff[(size_t)(k0 + r + i) * Hc + h0 + (lane << 2)];
            async_copy16(src,       &sh.Wl[buf][r + i][0]);
            async_copy16(src + 256, &sh.Wl[buf][r + i][256]);
        }
    };

#define ROWADD(r) { \
        acc[r][0] = __fadd_rn(acc[r][0], bf[0]); \
        acc[r][1] = __fadd_rn(acc[r][1], bf[1]); \
        acc[r][2] = __fadd_rn(acc[r][2], bf[2]); \
        acc[r][3] = __fadd_rn(acc[r][3], bf[3]); \
        acc[r][4] = __fadd_rn(acc[r][4], bf[4]); \
        acc[r][5] = __fadd_rn(acc[r][5], bf[5]); \
        acc[r][6] = __fadd_rn(acc[r][6], bf[6]); \
        acc[r][7] = __fadd_rn(acc[r][7], bf[7]); }

    uint2 pkv = *(const uint2*)bp;        // bytes for k-tile 0
    stageW(0, 0);
    __syncthreads();                      // prologue drain

    int cur = 0;
    for (int kt = 0; kt < 256; kt++) {
        uint2 pknx = pkv;
        if (kt < 255) {
            stageW(cur ^ 1, kt + 1);      // issue DMA, no wait
            pknx = *(const uint2*)(bp + ((kt + 1) << 3));
        }
        // Force the wave-shared spike bytes into SGPRs -> uniform branches.
        const unsigned w0 = __builtin_amdgcn_readfirstlane(pkv.x);
        const unsigned w1 = __builtin_amdgcn_readfirstlane(pkv.y);

        // Per-lane 32-bit LDS base for the current buffer (AS(3) pointer).
        const __attribute__((address_space(3))) float* lp =
            (const __attribute__((address_space(3))) float*)
                (&sh.Wl[cur][0][0]) + lane;

#pragma unroll
        for (int kk = 0; kk < 8; kk++) {
            const unsigned word = (kk < 4) ? w0 : w1;
            const unsigned byte = (word >> ((kk & 3) * 8)) & 0xFFu;
            if (byte) {                   // uniform: skip k entirely if no
                // 4x ds_read2st64_b32: words 512*kk + 64*j + lane, j=0..7.
                // offsets in 256-B units = 8*kk + j (compile-time, <=63).
                float2 q0, q1, q2, q3;
                asm volatile("ds_read2st64_b32 %0, %1 offset0:%c2 offset1:%c3"
                             : "=v"(q0) : "v"(lp), "n"(8 * kk + 0), "n"(8 * kk + 1));
                asm volatile("ds_read2st64_b32 %0, %1 offset0:%c2 offset1:%c3"
                             : "=v"(q1) : "v"(lp), "n"(8 * kk + 2), "n"(8 * kk + 3));
                asm volatile("ds_read2st64_b32 %0, %1 offset0:%c2 offset1:%c3"
                             : "=v"(q2) : "v"(lp), "n"(8 * kk + 4), "n"(8 * kk + 5));
                asm volatile("ds_read2st64_b32 %0, %1 offset0:%c2 offset1:%c3"
                             : "=v"(q3) : "v"(lp), "n"(8 * kk + 6), "n"(8 * kk + 7));
                asm volatile("s_waitcnt lgkmcnt(0)" ::: "memory");
                __builtin_amdgcn_sched_barrier(0);   // rule #18 fence
                const float bf[8] = {q0.x, q0.y, q1.x, q1.y,
                                     q2.x, q2.y, q3.x, q3.y};
                if (byte & 1u)   ROWADD(0)
                if (byte & 2u)   ROWADD(1)
                if (byte & 4u)   ROWADD(2)
                if (byte & 8u)   ROWADD(3)
                if (byte & 16u)  ROWADD(4)
                if (byte & 32u)  ROWADD(5)
                if (byte & 64u)  ROWADD(6)
                if (byte & 128u) ROWADD(7)
            }
        }

        // Eigen kc=320 panel boundary (320 = 40 tiles of 8; tail 128):
        // unfused fold into total, reset chain. Same k boundaries as R8.
        if (((kt + 1) % 40 == 0) || (kt == 255)) {
#pragma unroll
            for (int r = 0; r < 8; r++)
#pragma unroll
                for (int j = 0; j < 8; j++) {
                    tot[r][j] = __fadd_rn(tot[r][j], acc[r][j]);
                    acc[r][j] = 0.0f;
                }
        }

        __syncthreads();   // drains next-tile DMA (landed under compute)
        pkv = pknx;
        cur ^= 1;
    }

    // ---- Epilogue: two passes of 16 m-rows through Cl (Wl dead). ----
    // tot[r][j] is (m = w*8+r, h = j*64+lane). Pass p covers waves 2p,2p+1.
#pragma unroll
    for (int p = 0; p < 2; p++) {
        if ((w >> 1) == p) {
            const int mb = (w & 1) << 3;     // 0 or 8 within the pass tile
#pragma unroll
            for (int r = 0; r < 8; r++)
#pragma unroll
                for (int j = 0; j < 8; j++)
                    sh.Cl[mb + r][j * 64 + lane] = tot[r][j];
        }
        __syncthreads();
        // Store: per u, 64 h-rows x (4-lane group = 64-B contiguous seg).
        const int mq = (tid & 3) << 2;
#pragma unroll
        for (int u = 0; u < 8; u++) {
            const int hr = (u << 6) + (tid >> 2);
            float4 v;
            v.x = sh.Cl[mq + 0][hr];
            v.y = sh.Cl[mq + 1][hr];
            v.z = sh.Cl[mq + 2][hr];
            v.w = sh.Cl[mq + 3][hr];
            *(float4*)&Ct[(size_t)(h0 + hr) * 8192 + m0g + (p << 4) + mq] = v;
        }
        if (p == 0) __syncthreads();
    }
#undef ROWADD
}

// One wave (64 lanes) per h; lane = batch b. Scan state f32, unfused.
// Batch-mean via ballot/popcount (exact). Validated numerics — UNCHANGED
// (verbatim R1 version; Wt layout [Hc][B][T] = [Hc][8192]).
__global__ __launch_bounds__(256) void scan_kernel(
    const float* __restrict__ Wt,          // [Hc][B][T] f32 chunk-local
    const float* __restrict__ threshold,   // [H] f32 global
    const float* __restrict__ p_tau_mem,
    const float* __restrict__ p_tau_syn,
    const float* __restrict__ p_target,
    const float* __restrict__ p_lr,
    float* __restrict__ out,               // [B][H][T] f32 global
    int h_base)
{
    __shared__ float S[4 * 64 * 17];
    __shared__ unsigned int Bits[4][64][4];

    const int tid  = threadIdx.x;
    const int w    = tid >> 6;
    const int lane = tid & 63;            // batch b
    const int hl   = blockIdx.x * 4 + w;  // chunk-local h

    const float tau_mem = p_tau_mem[0];
    const float tau_syn = p_tau_syn[0];
    const float target  = p_target[0];
    const float lr      = p_lr[0];
    const float a_mem = (float)exp((double)__fdiv_rn(-0.001f, tau_mem));
    const float a_syn = (float)exp((double)__fdiv_rn(-0.001f, tau_syn));

    float i_syn = 0.0f, v_mem = 0.0f;
    float thr = threshold[h_base + hl];
    float fre = 0.0f;
    unsigned int bits[4] = {0u, 0u, 0u, 0u};

    const int st4 = tid & 3;
    const int sb  = (tid >> 2) & 63;

    for (int tc = 0; tc < 128; tc += 16) {
        __syncthreads();
#pragma unroll
        for (int hh = 0; hh < 4; hh++) {
            const int hg = blockIdx.x * 4 + hh;
            float4 v = *(const float4*)&Wt[(size_t)hg * 8192 + sb * 128 + tc + 4 * st4];
            float* row = &S[(hh * 64 + sb) * 17];
            row[4 * st4 + 0] = v.x;
            row[4 * st4 + 1] = v.y;
            row[4 * st4 + 2] = v.z;
            row[4 * st4 + 3] = v.w;
        }
        __syncthreads();

        const float* row = &S[(w * 64 + lane) * 17];
#pragma unroll
        for (int tt = 0; tt < 16; tt++) {
            const int t = tc + tt;
            const float wv = row[tt];
            i_syn = __fadd_rn(__fmul_rn(a_syn, i_syn), wv);
            v_mem = __fadd_rn(__fmul_rn(a_mem, v_mem), i_syn);
            const bool sp = (v_mem >= thr);
            const unsigned long long mask = __ballot(sp);
            if (sp) v_mem = __fsub_rn(v_mem, thr);
            const int cnt = __popcll(mask);
            const float rate = __fmul_rn((float)cnt, 0.015625f);
            fre = __fadd_rn(__fmul_rn(0.99f, fre), __fmul_rn(0.01f, rate));
            thr = __fadd_rn(thr, __fmul_rn(lr, __fsub_rn(fre, target)));
            if (sp) bits[t >> 5] |= (1u << (t & 31));
        }
    }

    __syncthreads();
    Bits[w][lane][0] = bits[0];
    Bits[w][lane][1] = bits[1];
    Bits[w][lane][2] = bits[2];
    Bits[w][lane][3] = bits[3];
    __syncthreads();

    for (int b = 0; b < 64; b++) {
        const unsigned int word = Bits[w][b][lane >> 4];
        float2 v;
        v.x = ((word >> ((2 * lane) & 31)) & 1u) ? 1.0f : 0.0f;
        v.y = ((word >> ((2 * lane + 1) & 31)) & 1u) ? 1.0f : 0.0f;
        *(float2*)&out[((size_t)b * 2048 + h_base + hl) * 128 + 2 * lane] = v;
    }
}

extern "C" void kernel_launch(void* const* d_in, const int* in_sizes, int n_in,
                              void* d_out, int out_size, void* d_ws, size_t ws_size,
                              hipStream_t stream) {
    const float* spikes    = (const float*)d_in[0];
    const float* weight    = (const float*)d_in[1];
    const float* strength  = (const float*)d_in[2];
    const float* threshold = (const float*)d_in[3];
    const float* tau_mem   = (const float*)d_in[4];
    const float* tau_syn   = (const float*)d_in[5];
    const float* target    = (const float*)d_in[6];
    const float* lr        = (const float*)d_in[7];

    float* out = (float*)d_out;

    // ws: Wt [Hc][8192] f32 + weff [2048][Hc] f32 + bitsT 2 MiB.
    int Hc = 2048;
    while (Hc > 512 && (size_t)Hc * 40960ull + 2097152ull > ws_size) Hc >>= 1;

    float* Wt   = (float*)d_ws;
    float* weff = (float*)d_ws + (size_t)Hc * 8192;
    unsigned char* bitsT = (unsigned char*)(weff + (size_t)2048 * Hc);

    bits_kernel<<<32768, 256, 0, stream>>>(spikes, bitsT);

    for (int hb = 0; hb < 2048; hb += Hc) {
        weff_kernel<<<2048, 256, 0, stream>>>(weight, strength, weff, hb, Hc);
        gemm_kernel<<<dim3(Hc / 512, 256), 256, 0, stream>>>(weff, bitsT, Wt, Hc);
        scan_kernel<<<Hc / 4, 256, 0, stream>>>(
            Wt, threshold, tau_mem, tau_syn, target, lr, out, hb);
    }
}

// Round 12
// 711.945 us; speedup vs baseline: 1.0602x; 1.0602x over previous
//
#include <hip/hip_runtime.h>
#include <math.h>

// B=64, I=K=2048, H=N=2048, T=128.  m = b*128 + t (M=8192).
// Numerics contract (VALIDATED GREEN): Eigen gebp kc=320 K-panels; per C
// element an ascending-k FMA chain within each 320-panel (register
// accumulator), panels combined by UNFUSED f32 adds (beta=0 first).
// Spikes are EXACT 0.0f/1.0f, so fma(1,b,acc)=__fadd_rn(acc,b) and
// fma(0,b,acc)=acc bit-for-bit -> skipping zero-spike terms is bit-exact.
// w_eff = __fmul_rn(weight, strength) rounded once. Scan: f32 state,
// unfused mul/add; exact batch mean via ballot/popcount; correctly-rounded
// expf via (float)exp((double)quotient).
//
// R12 = R10 inner loop verbatim (R11's forced read2+fence regressed:
// VALUBusy 31->24.6, compiler's counted-lgkmcnt pipelining was better).
// Change: 512-thread blocks (8 waves share one staged B-tile, which is
// m-independent) -> residency 8 -> 16 waves/CU so the per-CU LDS pipe
// (~360us busy), scalar unit (~165us) and VALU (~174us) overlap instead
// of serializing. Wave w owns m-rows 64*by + 8w .. +7 (tbyte (by&1)*8+w).
// Epilogue: 4 passes x 16 m-rows through Cl[16][517], 64-B segments.

__device__ __forceinline__ void async_copy16(const float* g, float* l) {
    __builtin_amdgcn_global_load_lds(
        (const __attribute__((address_space(1))) void*)g,
        (__attribute__((address_space(3))) void*)l, 16, 0, 0);
}

// weff[i][hl] = __fmul_rn(weight[i][h_base+hl], strength[i][h_base+hl])
__global__ __launch_bounds__(256) void weff_kernel(
    const float* __restrict__ weight, const float* __restrict__ strength,
    float* __restrict__ weff, int h_base, int Hc)
{
    const int i = blockIdx.x;  // input row 0..2047
    const float* wr = weight   + (size_t)i * 2048 + h_base;
    const float* sr = strength + (size_t)i * 2048 + h_base;
    float* dr = weff + (size_t)i * Hc;
    for (int c = threadIdx.x * 4; c < Hc; c += 1024) {
        float4 wv = *(const float4*)&wr[c];
        float4 sv = *(const float4*)&sr[c];
        float4 o;
        o.x = __fmul_rn(wv.x, sv.x);
        o.y = __fmul_rn(wv.y, sv.y);
        o.z = __fmul_rn(wv.z, sv.z);
        o.w = __fmul_rn(wv.w, sv.w);
        *(float4*)&dr[c] = o;
    }
}

// bitsT[b][tbyte][k]: bit r = (spikes[b][k][8*tbyte+r] != 0). One wave per
// (b,k): two ballots over 128 t, lanes 0..15 each emit one byte.
__global__ __launch_bounds__(256) void bits_kernel(
    const float* __restrict__ spikes, unsigned char* __restrict__ bitsT)
{
    const int tid  = threadIdx.x;
    const int w    = tid >> 6;
    const int lane = tid & 63;
    const int wid  = blockIdx.x * 4 + w;     // b*2048 + k
    const int b    = wid >> 11;
    const int k    = wid & 2047;
    const float2 v = *(const float2*)&spikes[((size_t)b * 2048 + k) * 128 + 2 * lane];
    const unsigned long long m0 = __ballot(v.x != 0.0f);  // bit l -> t=2l
    const unsigned long long m1 = __ballot(v.y != 0.0f);  // bit l -> t=2l+1
    if (lane < 16) {
        unsigned byte = 0;
#pragma unroll
        for (int q = 0; q < 4; q++) {
            byte |= (unsigned)((m0 >> (4 * lane + q)) & 1ull) << (2 * q);
            byte |= (unsigned)((m1 >> (4 * lane + q)) & 1ull) << (2 * q + 1);
        }
        bitsT[((size_t)b * 16 + lane) * 2048 + k] = (unsigned char)byte;
    }
}

union ShU {
    float Wl[2][8][512];    // 32 KiB: double-buffered weff k-tile (8 k-rows)
    float Cl[16][517];      // 33 KiB: epilogue transpose, 16 m-rows per pass
};

__global__ __launch_bounds__(512, 6) void gemm_kernel(
    const float* __restrict__ weff,          // [2048][Hc]
    const unsigned char* __restrict__ bits,  // [64][16][2048]
    float* __restrict__ Ct,                  // [Hc][M=8192]
    int Hc)
{
    __shared__ ShU sh;

    const int tid  = threadIdx.x;
    const int w    = tid >> 6;          // wave 0..7
    const int lane = tid & 63;
    const int h0   = blockIdx.x * 512;  // chunk-local h-tile
    const int by   = blockIdx.y;        // 0..127: b = by>>1, t-half = by&1
    const int b    = by >> 1;
    const int m0g  = by * 64;           // block's first m (64 m per block)
    const int wbyte = ((by & 1) << 3) + w;  // wave's t-byte (8 m-rows)

    float acc[8][8];   // acc[r][j]: m-row r, h = h0 + 64*j + lane
    float tot[8][8];   // running unfused panel total
#pragma unroll
    for (int r = 0; r < 8; r++)
#pragma unroll
        for (int j = 0; j < 8; j++) { acc[r][j] = 0.0f; tot[r][j] = 0.0f; }

    const unsigned char* bp = bits + (((size_t)b * 16 + wbyte) << 11);

    // Stage k-tile kt (8 rows x 512 cols = 16 KiB) into buffer buf.
    // Wave w covers row w (one k-row, 2 KiB) as 2 DMA halves.
    auto stageW = [&](int buf, int kt) {
        const int k0 = kt << 3;
        const float* src = &weff[(size_t)(k0 + w) * Hc + h0 + (lane << 2)];
        async_copy16(src,       &sh.Wl[buf][w][0]);
        async_copy16(src + 256, &sh.Wl[buf][w][256]);
    };

#define ROWADD(r) { \
        acc[r][0] = __fadd_rn(acc[r][0], bf[0]); \
        acc[r][1] = __fadd_rn(acc[r][1], bf[1]); \
        acc[r][2] = __fadd_rn(acc[r][2], bf[2]); \
        acc[r][3] = __fadd_rn(acc[r][3], bf[3]); \
        acc[r][4] = __fadd_rn(acc[r][4], bf[4]); \
        acc[r][5] = __fadd_rn(acc[r][5], bf[5]); \
        acc[r][6] = __fadd_rn(acc[r][6], bf[6]); \
        acc[r][7] = __fadd_rn(acc[r][7], bf[7]); }

    uint2 pkv = *(const uint2*)bp;        // bytes for k-tile 0
    stageW(0, 0);
    __syncthreads();                      // prologue drain

    int cur = 0;
    for (int kt = 0; kt < 256; kt++) {
        uint2 pknx = pkv;
        if (kt < 255) {
            stageW(cur ^ 1, kt + 1);      // issue DMA, no wait
            pknx = *(const uint2*)(bp + ((kt + 1) << 3));
        }
        // Force the wave-shared spike bytes into SGPRs -> uniform branches.
        const unsigned w0 = __builtin_amdgcn_readfirstlane(pkv.x);
        const unsigned w1 = __builtin_amdgcn_readfirstlane(pkv.y);

        // Per-lane base; read offsets are compile-time immediates
        // (kk*2048 + j*256 bytes). Compiler schedules with counted lgkmcnt.
        const float* wrow = &sh.Wl[cur][0][0] + lane;

#pragma unroll
        for (int kk = 0; kk < 8; kk++) {
            const unsigned word = (kk < 4) ? w0 : w1;
            const unsigned byte = (word >> ((kk & 3) * 8)) & 0xFFu;
            if (byte) {                   // uniform: skip k entirely if no
                float bf[8];              // spike in this wave's 8 m-rows
#pragma unroll
                for (int j = 0; j < 8; j++)
                    bf[j] = wrow[kk * 512 + j * 64];  // 64 consec words: free
                if (byte & 1u)   ROWADD(0)
                if (byte & 2u)   ROWADD(1)
                if (byte & 4u)   ROWADD(2)
                if (byte & 8u)   ROWADD(3)
                if (byte & 16u)  ROWADD(4)
                if (byte & 32u)  ROWADD(5)
                if (byte & 64u)  ROWADD(6)
                if (byte & 128u) ROWADD(7)
            }
        }

        // Eigen kc=320 panel boundary (320 = 40 tiles of 8; tail 128):
        // unfused fold into total, reset chain. Same k boundaries as R8.
        if (((kt + 1) % 40 == 0) || (kt == 255)) {
#pragma unroll
            for (int r = 0; r < 8; r++)
#pragma unroll
                for (int j = 0; j < 8; j++) {
                    tot[r][j] = __fadd_rn(tot[r][j], acc[r][j]);
                    acc[r][j] = 0.0f;
                }
        }

        __syncthreads();   // drains next-tile DMA (landed under compute)
        pkv = pknx;
        cur ^= 1;
    }

    // ---- Epilogue: 4 passes of 16 m-rows through Cl (Wl dead). ----
    // tot[r][j] is (m = m0g + 8w + r, h = h0 + 64j + lane).
    // Pass p covers waves 2p, 2p+1.
#pragma unroll
    for (int p = 0; p < 4; p++) {
        if ((w >> 1) == p) {
            const int mb = (w & 1) << 3;     // 0 or 8 within the pass tile
#pragma unroll
            for (int r = 0; r < 8; r++)
#pragma unroll
                for (int j = 0; j < 8; j++)
                    sh.Cl[mb + r][j * 64 + lane] = tot[r][j];
        }
        __syncthreads();
        // Store: per (s,instr), each 4-lane group writes one 64-B
        // contiguous segment of a Ct h-row (R10-proven clean pattern).
        const int mq = (tid & 3) << 2;
#pragma unroll
        for (int s = 0; s < 4; s++) {
            const int hr = (s << 7) + (tid >> 2);
            float4 v;
            v.x = sh.Cl[mq + 0][hr];
            v.y = sh.Cl[mq + 1][hr];
            v.z = sh.Cl[mq + 2][hr];
            v.w = sh.Cl[mq + 3][hr];
            *(float4*)&Ct[(size_t)(h0 + hr) * 8192 + m0g + (p << 4) + mq] = v;
        }
        if (p < 3) __syncthreads();
    }
#undef ROWADD
}

// One wave (64 lanes) per h; lane = batch b. Scan state f32, unfused.
// Batch-mean via ballot/popcount (exact). Validated numerics — UNCHANGED
// (verbatim R1 version; Wt layout [Hc][B][T] = [Hc][8192]).
__global__ __launch_bounds__(256) void scan_kernel(
    const float* __restrict__ Wt,          // [Hc][B][T] f32 chunk-local
    const float* __restrict__ threshold,   // [H] f32 global
    const float* __restrict__ p_tau_mem,
    const float* __restrict__ p_tau_syn,
    const float* __restrict__ p_target,
    const float* __restrict__ p_lr,
    float* __restrict__ out,               // [B][H][T] f32 global
    int h_base)
{
    __shared__ float S[4 * 64 * 17];
    __shared__ unsigned int Bits[4][64][4];

    const int tid  = threadIdx.x;
    const int w    = tid >> 6;
    const int lane = tid & 63;            // batch b
    const int hl   = blockIdx.x * 4 + w;  // chunk-local h

    const float tau_mem = p_tau_mem[0];
    const float tau_syn = p_tau_syn[0];
    const float target  = p_target[0];
    const float lr      = p_lr[0];
    const float a_mem = (float)exp((double)__fdiv_rn(-0.001f, tau_mem));
    const float a_syn = (float)exp((double)__fdiv_rn(-0.001f, tau_syn));

    float i_syn = 0.0f, v_mem = 0.0f;
    float thr = threshold[h_base + hl];
    float fre = 0.0f;
    unsigned int bits[4] = {0u, 0u, 0u, 0u};

    const int st4 = tid & 3;
    const int sb  = (tid >> 2) & 63;

    for (int tc = 0; tc < 128; tc += 16) {
        __syncthreads();
#pragma unroll
        for (int hh = 0; hh < 4; hh++) {
            const int hg = blockIdx.x * 4 + hh;
            float4 v = *(const float4*)&Wt[(size_t)hg * 8192 + sb * 128 + tc + 4 * st4];
            float* row = &S[(hh * 64 + sb) * 17];
            row[4 * st4 + 0] = v.x;
            row[4 * st4 + 1] = v.y;
            row[4 * st4 + 2] = v.z;
            row[4 * st4 + 3] = v.w;
        }
        __syncthreads();

        const float* row = &S[(w * 64 + lane) * 17];
#pragma unroll
        for (int tt = 0; tt < 16; tt++) {
            const int t = tc + tt;
            const float wv = row[tt];
            i_syn = __fadd_rn(__fmul_rn(a_syn, i_syn), wv);
            v_mem = __fadd_rn(__fmul_rn(a_mem, v_mem), i_syn);
            const bool sp = (v_mem >= thr);
            const unsigned long long mask = __ballot(sp);
            if (sp) v_mem = __fsub_rn(v_mem, thr);
            const int cnt = __popcll(mask);
            const float rate = __fmul_rn((float)cnt, 0.015625f);
            fre = __fadd_rn(__fmul_rn(0.99f, fre), __fmul_rn(0.01f, rate));
            thr = __fadd_rn(thr, __fmul_rn(lr, __fsub_rn(fre, target)));
            if (sp) bits[t >> 5] |= (1u << (t & 31));
        }
    }

    __syncthreads();
    Bits[w][lane][0] = bits[0];
    Bits[w][lane][1] = bits[1];
    Bits[w][lane][2] = bits[2];
    Bits[w][lane][3] = bits[3];
    __syncthreads();

    for (int b = 0; b < 64; b++) {
        const unsigned int word = Bits[w][b][lane >> 4];
        float2 v;
        v.x = ((word >> ((2 * lane) & 31)) & 1u) ? 1.0f : 0.0f;
        v.y = ((word >> ((2 * lane + 1) & 31)) & 1u) ? 1.0f : 0.0f;
        *(float2*)&out[((size_t)b * 2048 + h_base + hl) * 128 + 2 * lane] = v;
    }
}

extern "C" void kernel_launch(void* const* d_in, const int* in_sizes, int n_in,
                              void* d_out, int out_size, void* d_ws, size_t ws_size,
                              hipStream_t stream) {
    const float* spikes    = (const float*)d_in[0];
    const float* weight    = (const float*)d_in[1];
    const float* strength  = (const float*)d_in[2];
    const float* threshold = (const float*)d_in[3];
    const float* tau_mem   = (const float*)d_in[4];
    const float* tau_syn   = (const float*)d_in[5];
    const float* target    = (const float*)d_in[6];
    const float* lr        = (const float*)d_in[7];

    float* out = (float*)d_out;

    // ws: Wt [Hc][8192] f32 + weff [2048][Hc] f32 + bitsT 2 MiB.
    int Hc = 2048;
    while (Hc > 512 && (size_t)Hc * 40960ull + 2097152ull > ws_size) Hc >>= 1;

    float* Wt   = (float*)d_ws;
    float* weff = (float*)d_ws + (size_t)Hc * 8192;
    unsigned char* bitsT = (unsigned char*)(weff + (size_t)2048 * Hc);

    bits_kernel<<<32768, 256, 0, stream>>>(spikes, bitsT);

    for (int hb = 0; hb < 2048; hb += Hc) {
        weff_kernel<<<2048, 256, 0, stream>>>(weight, strength, weff, hb, Hc);
        gemm_kernel<<<dim3(Hc / 512, 128), 512, 0, stream>>>(weff, bitsT, Wt, Hc);
        scan_kernel<<<Hc / 4, 256, 0, stream>>>(
            Wt, threshold, tau_mem, tau_syn, target, lr, out, hb);
    }
}

// Round 13
// 545.389 us; speedup vs baseline: 1.3840x; 1.3054x over previous
//
#include <hip/hip_runtime.h>
#include <math.h>

// B=64, I=K=2048, H=N=2048, T=128.  m = b*128 + t (M=8192).
// Numerics contract (VALIDATED GREEN): Eigen gebp kc=320 K-panels; per C
// element an ascending-k FMA chain within each 320-panel (register
// accumulator), panels combined by UNFUSED f32 adds (beta=0 first).
// Spikes are EXACT 0.0f/1.0f, so fma(1,b,acc)=__fadd_rn(acc,b) and
// fma(0,b,acc)=acc bit-for-bit -> skipping zero-spike terms is bit-exact.
// w_eff = __fmul_rn(weight, strength) rounded once. Scan: f32 state,
// unfused mul/add; exact batch mean via ballot/popcount; correctly-rounded
// expf via (float)exp((double)quotient).
//
// R13 = R12 with ONE token changed: __launch_bounds__(512,6) -> (512,4).
// R12's bound=6 made the allocator cap at 40 VGPRs and spill acc/tot to
// scratch (WRITE 562MB, FETCH 271MB of pure spill) -- yet still 557us at
// 47% occupancy, proving the 16-wave/CU overlap works. bound=4 keeps
// 2 blocks/CU x 8 waves = 16 waves/CU with a 512-VGPR budget: no spill,
// same overlap. Inner loop R10-verbatim (bit-exact).

__device__ __forceinline__ void async_copy16(const float* g, float* l) {
    __builtin_amdgcn_global_load_lds(
        (const __attribute__((address_space(1))) void*)g,
        (__attribute__((address_space(3))) void*)l, 16, 0, 0);
}

// weff[i][hl] = __fmul_rn(weight[i][h_base+hl], strength[i][h_base+hl])
__global__ __launch_bounds__(256) void weff_kernel(
    const float* __restrict__ weight, const float* __restrict__ strength,
    float* __restrict__ weff, int h_base, int Hc)
{
    const int i = blockIdx.x;  // input row 0..2047
    const float* wr = weight   + (size_t)i * 2048 + h_base;
    const float* sr = strength + (size_t)i * 2048 + h_base;
    float* dr = weff + (size_t)i * Hc;
    for (int c = threadIdx.x * 4; c < Hc; c += 1024) {
        float4 wv = *(const float4*)&wr[c];
        float4 sv = *(const float4*)&sr[c];
        float4 o;
        o.x = __fmul_rn(wv.x, sv.x);
        o.y = __fmul_rn(wv.y, sv.y);
        o.z = __fmul_rn(wv.z, sv.z);
        o.w = __fmul_rn(wv.w, sv.w);
        *(float4*)&dr[c] = o;
    }
}

// bitsT[b][tbyte][k]: bit r = (spikes[b][k][8*tbyte+r] != 0). One wave per
// (b,k): two ballots over 128 t, lanes 0..15 each emit one byte.
__global__ __launch_bounds__(256) void bits_kernel(
    const float* __restrict__ spikes, unsigned char* __restrict__ bitsT)
{
    const int tid  = threadIdx.x;
    const int w    = tid >> 6;
    const int lane = tid & 63;
    const int wid  = blockIdx.x * 4 + w;     // b*2048 + k
    const int b    = wid >> 11;
    const int k    = wid & 2047;
    const float2 v = *(const float2*)&spikes[((size_t)b * 2048 + k) * 128 + 2 * lane];
    const unsigned long long m0 = __ballot(v.x != 0.0f);  // bit l -> t=2l
    const unsigned long long m1 = __ballot(v.y != 0.0f);  // bit l -> t=2l+1
    if (lane < 16) {
        unsigned byte = 0;
#pragma unroll
        for (int q = 0; q < 4; q++) {
            byte |= (unsigned)((m0 >> (4 * lane + q)) & 1ull) << (2 * q);
            byte |= (unsigned)((m1 >> (4 * lane + q)) & 1ull) << (2 * q + 1);
        }
        bitsT[((size_t)b * 16 + lane) * 2048 + k] = (unsigned char)byte;
    }
}

union ShU {
    float Wl[2][8][512];    // 32 KiB: double-buffered weff k-tile (8 k-rows)
    float Cl[16][517];      // 33 KiB: epilogue transpose, 16 m-rows per pass
};

__global__ __launch_bounds__(512, 4) void gemm_kernel(
    const float* __restrict__ weff,          // [2048][Hc]
    const unsigned char* __restrict__ bits,  // [64][16][2048]
    float* __restrict__ Ct,                  // [Hc][M=8192]
    int Hc)
{
    __shared__ ShU sh;

    const int tid  = threadIdx.x;
    const int w    = tid >> 6;          // wave 0..7
    const int lane = tid & 63;
    const int h0   = blockIdx.x * 512;  // chunk-local h-tile
    const int by   = blockIdx.y;        // 0..127: b = by>>1, t-half = by&1
    const int b    = by >> 1;
    const int m0g  = by * 64;           // block's first m (64 m per block)
    const int wbyte = ((by & 1) << 3) + w;  // wave's t-byte (8 m-rows)

    float acc[8][8];   // acc[r][j]: m-row r, h = h0 + 64*j + lane
    float tot[8][8];   // running unfused panel total
#pragma unroll
    for (int r = 0; r < 8; r++)
#pragma unroll
        for (int j = 0; j < 8; j++) { acc[r][j] = 0.0f; tot[r][j] = 0.0f; }

    const unsigned char* bp = bits + (((size_t)b * 16 + wbyte) << 11);

    // Stage k-tile kt (8 rows x 512 cols = 16 KiB) into buffer buf.
    // Wave w covers row w (one k-row, 2 KiB) as 2 DMA halves.
    auto stageW = [&](int buf, int kt) {
        const int k0 = kt << 3;
        const float* src = &weff[(size_t)(k0 + w) * Hc + h0 + (lane << 2)];
        async_copy16(src,       &sh.Wl[buf][w][0]);
        async_copy16(src + 256, &sh.Wl[buf][w][256]);
    };

#define ROWADD(r) { \
        acc[r][0] = __fadd_rn(acc[r][0], bf[0]); \
        acc[r][1] = __fadd_rn(acc[r][1], bf[1]); \
        acc[r][2] = __fadd_rn(acc[r][2], bf[2]); \
        acc[r][3] = __fadd_rn(acc[r][3], bf[3]); \
        acc[r][4] = __fadd_rn(acc[r][4], bf[4]); \
        acc[r][5] = __fadd_rn(acc[r][5], bf[5]); \
        acc[r][6] = __fadd_rn(acc[r][6], bf[6]); \
        acc[r][7] = __fadd_rn(acc[r][7], bf[7]); }

    uint2 pkv = *(const uint2*)bp;        // bytes for k-tile 0
    stageW(0, 0);
    __syncthreads();                      // prologue drain

    int cur = 0;
    for (int kt = 0; kt < 256; kt++) {
        uint2 pknx = pkv;
        if (kt < 255) {
            stageW(cur ^ 1, kt + 1);      // issue DMA, no wait
            pknx = *(const uint2*)(bp + ((kt + 1) << 3));
        }
        // Force the wave-shared spike bytes into SGPRs -> uniform branches.
        const unsigned w0 = __builtin_amdgcn_readfirstlane(pkv.x);
        const unsigned w1 = __builtin_amdgcn_readfirstlane(pkv.y);

        // Per-lane base; read offsets are compile-time immediates
        // (kk*2048 + j*256 bytes). Compiler schedules with counted lgkmcnt.
        const float* wrow = &sh.Wl[cur][0][0] + lane;

#pragma unroll
        for (int kk = 0; kk < 8; kk++) {
            const unsigned word = (kk < 4) ? w0 : w1;
            const unsigned byte = (word >> ((kk & 3) * 8)) & 0xFFu;
            if (byte) {                   // uniform: skip k entirely if no
                float bf[8];              // spike in this wave's 8 m-rows
#pragma unroll
                for (int j = 0; j < 8; j++)
                    bf[j] = wrow[kk * 512 + j * 64];  // 64 consec words: free
                if (byte & 1u)   ROWADD(0)
                if (byte & 2u)   ROWADD(1)
                if (byte & 4u)   ROWADD(2)
                if (byte & 8u)   ROWADD(3)
                if (byte & 16u)  ROWADD(4)
                if (byte & 32u)  ROWADD(5)
                if (byte & 64u)  ROWADD(6)
                if (byte & 128u) ROWADD(7)
            }
        }

        // Eigen kc=320 panel boundary (320 = 40 tiles of 8; tail 128):
        // unfused fold into total, reset chain. Same k boundaries as R8.
        if (((kt + 1) % 40 == 0) || (kt == 255)) {
#pragma unroll
            for (int r = 0; r < 8; r++)
#pragma unroll
                for (int j = 0; j < 8; j++) {
                    tot[r][j] = __fadd_rn(tot[r][j], acc[r][j]);
                    acc[r][j] = 0.0f;
                }
        }

        __syncthreads();   // drains next-tile DMA (landed under compute)
        pkv = pknx;
        cur ^= 1;
    }

    // ---- Epilogue: 4 passes of 16 m-rows through Cl (Wl dead). ----
    // tot[r][j] is (m = m0g + 8w + r, h = h0 + 64j + lane).
    // Pass p covers waves 2p, 2p+1.
#pragma unroll
    for (int p = 0; p < 4; p++) {
        if ((w >> 1) == p) {
            const int mb = (w & 1) << 3;     // 0 or 8 within the pass tile
#pragma unroll
            for (int r = 0; r < 8; r++)
#pragma unroll
                for (int j = 0; j < 8; j++)
                    sh.Cl[mb + r][j * 64 + lane] = tot[r][j];
        }
        __syncthreads();
        // Store: per (s,instr), each 4-lane group writes one 64-B
        // contiguous segment of a Ct h-row (R10-proven clean pattern).
        const int mq = (tid & 3) << 2;
#pragma unroll
        for (int s = 0; s < 4; s++) {
            const int hr = (s << 7) + (tid >> 2);
            float4 v;
            v.x = sh.Cl[mq + 0][hr];
            v.y = sh.Cl[mq + 1][hr];
            v.z = sh.Cl[mq + 2][hr];
            v.w = sh.Cl[mq + 3][hr];
            *(float4*)&Ct[(size_t)(h0 + hr) * 8192 + m0g + (p << 4) + mq] = v;
        }
        if (p < 3) __syncthreads();
    }
#undef ROWADD
}

// One wave (64 lanes) per h; lane = batch b. Scan state f32, unfused.
// Batch-mean via ballot/popcount (exact). Validated numerics — UNCHANGED
// (verbatim R1 version; Wt layout [Hc][B][T] = [Hc][8192]).
__global__ __launch_bounds__(256) void scan_kernel(
    const float* __restrict__ Wt,          // [Hc][B][T] f32 chunk-local
    const float* __restrict__ threshold,   // [H] f32 global
    const float* __restrict__ p_tau_mem,
    const float* __restrict__ p_tau_syn,
    const float* __restrict__ p_target,
    const float* __restrict__ p_lr,
    float* __restrict__ out,               // [B][H][T] f32 global
    int h_base)
{
    __shared__ float S[4 * 64 * 17];
    __shared__ unsigned int Bits[4][64][4];

    const int tid  = threadIdx.x;
    const int w    = tid >> 6;
    const int lane = tid & 63;            // batch b
    const int hl   = blockIdx.x * 4 + w;  // chunk-local h

    const float tau_mem = p_tau_mem[0];
    const float tau_syn = p_tau_syn[0];
    const float target  = p_target[0];
    const float lr      = p_lr[0];
    const float a_mem = (float)exp((double)__fdiv_rn(-0.001f, tau_mem));
    const float a_syn = (float)exp((double)__fdiv_rn(-0.001f, tau_syn));

    float i_syn = 0.0f, v_mem = 0.0f;
    float thr = threshold[h_base + hl];
    float fre = 0.0f;
    unsigned int bits[4] = {0u, 0u, 0u, 0u};

    const int st4 = tid & 3;
    const int sb  = (tid >> 2) & 63;

    for (int tc = 0; tc < 128; tc += 16) {
        __syncthreads();
#pragma unroll
        for (int hh = 0; hh < 4; hh++) {
            const int hg = blockIdx.x * 4 + hh;
            float4 v = *(const float4*)&Wt[(size_t)hg * 8192 + sb * 128 + tc + 4 * st4];
            float* row = &S[(hh * 64 + sb) * 17];
            row[4 * st4 + 0] = v.x;
            row[4 * st4 + 1] = v.y;
            row[4 * st4 + 2] = v.z;
            row[4 * st4 + 3] = v.w;
        }
        __syncthreads();

        const float* row = &S[(w * 64 + lane) * 17];
#pragma unroll
        for (int tt = 0; tt < 16; tt++) {
            const int t = tc + tt;
            const float wv = row[tt];
            i_syn = __fadd_rn(__fmul_rn(a_syn, i_syn), wv);
            v_mem = __fadd_rn(__fmul_rn(a_mem, v_mem), i_syn);
            const bool sp = (v_mem >= thr);
            const unsigned long long mask = __ballot(sp);
            if (sp) v_mem = __fsub_rn(v_mem, thr);
            const int cnt = __popcll(mask);
            const float rate = __fmul_rn((float)cnt, 0.015625f);
            fre = __fadd_rn(__fmul_rn(0.99f, fre), __fmul_rn(0.01f, rate));
            thr = __fadd_rn(thr, __fmul_rn(lr, __fsub_rn(fre, target)));
            if (sp) bits[t >> 5] |= (1u << (t & 31));
        }
    }

    __syncthreads();
    Bits[w][lane][0] = bits[0];
    Bits[w][lane][1] = bits[1];
    Bits[w][lane][2] = bits[2];
    Bits[w][lane][3] = bits[3];
    __syncthreads();

    for (int b = 0; b < 64; b++) {
        const unsigned int word = Bits[w][b][lane >> 4];
        float2 v;
        v.x = ((word >> ((2 * lane) & 31)) & 1u) ? 1.0f : 0.0f;
        v.y = ((word >> ((2 * lane + 1) & 31)) & 1u) ? 1.0f : 0.0f;
        *(float2*)&out[((size_t)b * 2048 + h_base + hl) * 128 + 2 * lane] = v;
    }
}

extern "C" void kernel_launch(void* const* d_in, const int* in_sizes, int n_in,
                              void* d_out, int out_size, void* d_ws, size_t ws_size,
                              hipStream_t stream) {
    const float* spikes    = (const float*)d_in[0];
    const float* weight    = (const float*)d_in[1];
    const float* strength  = (const float*)d_in[2];
    const float* threshold = (const float*)d_in[3];
    const float* tau_mem   = (const float*)d_in[4];
    const float* tau_syn   = (const float*)d_in[5];
    const float* target    = (const float*)d_in[6];
    const float* lr        = (const float*)d_in[7];

    float* out = (float*)d_out;

    // ws: Wt [Hc][8192] f32 + weff [2048][Hc] f32 + bitsT 2 MiB.
    int Hc = 2048;
    while (Hc > 512 && (size_t)Hc * 40960ull + 2097152ull > ws_size) Hc >>= 1;

    float* Wt   = (float*)d_ws;
    float* weff = (float*)d_ws + (size_t)Hc * 8192;
    unsigned char* bitsT = (unsigned char*)(weff + (size_t)2048 * Hc);

    bits_kernel<<<32768, 256, 0, stream>>>(spikes, bitsT);

    for (int hb = 0; hb < 2048; hb += Hc) {
        weff_kernel<<<2048, 256, 0, stream>>>(weight, strength, weff, hb, Hc);
        gemm_kernel<<<dim3(Hc / 512, 128), 512, 0, stream>>>(weff, bitsT, Wt, Hc);
        scan_kernel<<<Hc / 4, 256, 0, stream>>>(
            Wt, threshold, tau_mem, tau_syn, target, lr, out, hb);
    }
}

// Round 14
// 515.286 us; speedup vs baseline: 1.4649x; 1.0584x over previous
//
#include <hip/hip_runtime.h>
#include <math.h>

// B=64, I=K=2048, H=N=2048, T=128.  m = b*128 + t (M=8192).
// Numerics contract (VALIDATED GREEN): Eigen gebp kc=320 K-panels; per C
// element an ascending-k FMA chain within each 320-panel (register
// accumulator), panels combined by UNFUSED f32 adds (beta=0 first).
// Spikes are EXACT 0.0f/1.0f, so fma(1,b,acc)=__fadd_rn(acc,b) and
// fma(0,b,acc)=acc bit-for-bit -> skipping zero-spike terms is bit-exact.
// w_eff = __fmul_rn(weight, strength) rounded once. Scan: f32 state,
// unfused mul/add; exact batch mean via ballot/popcount; correctly-rounded
// expf via (float)exp((double)quotient).
//
// R14 = R13 with the LDS instruction count halved. R13 sits at ~92% of the
// ds_read_b32 issue roofline (16 waves/CU x 9340 reads x 5.8cyc = 361us vs
// 391 measured). Fix: pre-swizzle weff within each 512-col block so the
// pair (j=2*j2, j=2*j2+1) for a lane is ADJACENT in LDS:
//   stored position p = j2*128 + lane*2 + e  <-  h = 128*j2 + 64*e + lane.
// Inner loop then does 4x ds_read_b64 per active k (lanes cover 128
// consecutive words -> conflict-free). Same weff element reaches the same
// bf[j] chain slot -> bit-identical. DMA staging & epilogue R13-verbatim.

__device__ __forceinline__ void async_copy16(const float* g, float* l) {
    __builtin_amdgcn_global_load_lds(
        (const __attribute__((address_space(1))) void*)g,
        (__attribute__((address_space(3))) void*)l, 16, 0, 0);
}

// weff_sw[i][blk*512 + j2*128 + l2*2 + e] =
//     __fmul_rn(weight, strength)[i][h_base + blk*512 + j2*128 + 64*e + l2]
__global__ __launch_bounds__(256) void weff_kernel(
    const float* __restrict__ weight, const float* __restrict__ strength,
    float* __restrict__ weff, int h_base, int Hc)
{
    const int i = blockIdx.x;  // input row 0..2047
    const float* wr = weight   + (size_t)i * 2048 + h_base;
    const float* sr = strength + (size_t)i * 2048 + h_base;
    float* dr = weff + (size_t)i * Hc;
    for (int p = threadIdx.x * 4; p < Hc; p += 1024) {
        const int blk = p >> 9;
        const int q   = p & 511;          // = j2*128 + l2*2 (p%4==0 -> e=0)
        const int j2  = q >> 7;
        const int l2  = (q & 127) >> 1;
        const int h   = (blk << 9) + (j2 << 7) + l2;
        float2 wa = *(const float2*)&wr[h];
        float2 wb = *(const float2*)&wr[h + 64];
        float2 sa = *(const float2*)&sr[h];
        float2 sb = *(const float2*)&sr[h + 64];
        float4 o;
        o.x = __fmul_rn(wa.x, sa.x);   // (j2, l2,   e=0)
        o.y = __fmul_rn(wb.x, sb.x);   // (j2, l2,   e=1)
        o.z = __fmul_rn(wa.y, sa.y);   // (j2, l2+1, e=0)
        o.w = __fmul_rn(wb.y, sb.y);   // (j2, l2+1, e=1)
        *(float4*)&dr[p] = o;
    }
}

// bitsT[b][tbyte][k]: bit r = (spikes[b][k][8*tbyte+r] != 0). One wave per
// (b,k): two ballots over 128 t, lanes 0..15 each emit one byte.
__global__ __launch_bounds__(256) void bits_kernel(
    const float* __restrict__ spikes, unsigned char* __restrict__ bitsT)
{
    const int tid  = threadIdx.x;
    const int w    = tid >> 6;
    const int lane = tid & 63;
    const int wid  = blockIdx.x * 4 + w;     // b*2048 + k
    const int b    = wid >> 11;
    const int k    = wid & 2047;
    const float2 v = *(const float2*)&spikes[((size_t)b * 2048 + k) * 128 + 2 * lane];
    const unsigned long long m0 = __ballot(v.x != 0.0f);  // bit l -> t=2l
    const unsigned long long m1 = __ballot(v.y != 0.0f);  // bit l -> t=2l+1
    if (lane < 16) {
        unsigned byte = 0;
#pragma unroll
        for (int q = 0; q < 4; q++) {
            byte |= (unsigned)((m0 >> (4 * lane + q)) & 1ull) << (2 * q);
            byte |= (unsigned)((m1 >> (4 * lane + q)) & 1ull) << (2 * q + 1);
        }
        bitsT[((size_t)b * 16 + lane) * 2048 + k] = (unsigned char)byte;
    }
}

union ShU {
    float Wl[2][8][512];    // 32 KiB: double-buffered weff k-tile (8 k-rows)
    float Cl[16][517];      // 33 KiB: epilogue transpose, 16 m-rows per pass
};

__global__ __launch_bounds__(512, 4) void gemm_kernel(
    const float* __restrict__ weff,          // [2048][Hc] (block-swizzled)
    const unsigned char* __restrict__ bits,  // [64][16][2048]
    float* __restrict__ Ct,                  // [Hc][M=8192]
    int Hc)
{
    __shared__ ShU sh;

    const int tid  = threadIdx.x;
    const int w    = tid >> 6;          // wave 0..7
    const int lane = tid & 63;
    const int h0   = blockIdx.x * 512;  // chunk-local h-tile (512-aligned)
    const int by   = blockIdx.y;        // 0..127: b = by>>1, t-half = by&1
    const int b    = by >> 1;
    const int m0g  = by * 64;           // block's first m (64 m per block)
    const int wbyte = ((by & 1) << 3) + w;  // wave's t-byte (8 m-rows)

    float acc[8][8];   // acc[r][j]: m-row r, h = h0 + 64*j + lane
    float tot[8][8];   // running unfused panel total
#pragma unroll
    for (int r = 0; r < 8; r++)
#pragma unroll
        for (int j = 0; j < 8; j++) { acc[r][j] = 0.0f; tot[r][j] = 0.0f; }

    const unsigned char* bp = bits + (((size_t)b * 16 + wbyte) << 11);

    // Stage k-tile kt (8 rows x 512 cols = 16 KiB) into buffer buf.
    // Wave w covers row w (one k-row, 2 KiB) as 2 DMA halves. The swizzled
    // row is still 16-B contiguous in global -> linear LDS dest is fine.
    auto stageW = [&](int buf, int kt) {
        const int k0 = kt << 3;
        const float* src = &weff[(size_t)(k0 + w) * Hc + h0 + (lane << 2)];
        async_copy16(src,       &sh.Wl[buf][w][0]);
        async_copy16(src + 256, &sh.Wl[buf][w][256]);
    };

#define ROWADD(r) { \
        acc[r][0] = __fadd_rn(acc[r][0], bf[0]); \
        acc[r][1] = __fadd_rn(acc[r][1], bf[1]); \
        acc[r][2] = __fadd_rn(acc[r][2], bf[2]); \
        acc[r][3] = __fadd_rn(acc[r][3], bf[3]); \
        acc[r][4] = __fadd_rn(acc[r][4], bf[4]); \
        acc[r][5] = __fadd_rn(acc[r][5], bf[5]); \
        acc[r][6] = __fadd_rn(acc[r][6], bf[6]); \
        acc[r][7] = __fadd_rn(acc[r][7], bf[7]); }

    uint2 pkv = *(const uint2*)bp;        // bytes for k-tile 0
    stageW(0, 0);
    __syncthreads();                      // prologue drain

    int cur = 0;
    for (int kt = 0; kt < 256; kt++) {
        uint2 pknx = pkv;
        if (kt < 255) {
            stageW(cur ^ 1, kt + 1);      // issue DMA, no wait
            pknx = *(const uint2*)(bp + ((kt + 1) << 3));
        }
        // Force the wave-shared spike bytes into SGPRs -> uniform branches.
        const unsigned w0 = __builtin_amdgcn_readfirstlane(pkv.x);
        const unsigned w1 = __builtin_amdgcn_readfirstlane(pkv.y);

        // Per-lane base (8-B aligned); offsets kk*2048 + j2*512 bytes are
        // compile-time immediates. 4x ds_read_b64 per active k; lanes
        // cover 128 consecutive words -> conflict-free.
        const float* wrow = &sh.Wl[cur][0][0] + (lane << 1);

#pragma unroll
        for (int kk = 0; kk < 8; kk++) {
            const unsigned word = (kk < 4) ? w0 : w1;
            const unsigned byte = (word >> ((kk & 3) * 8)) & 0xFFu;
            if (byte) {                   // uniform: skip k entirely if no
                float bf[8];              // spike in this wave's 8 m-rows
#pragma unroll
                for (int j2 = 0; j2 < 4; j2++) {
                    const float2 q =
                        *(const float2*)&wrow[kk * 512 + j2 * 128];
                    bf[2 * j2]     = q.x;   // h = 64*(2*j2)   + lane
                    bf[2 * j2 + 1] = q.y;   // h = 64*(2*j2+1) + lane
                }
                if (byte & 1u)   ROWADD(0)
                if (byte & 2u)   ROWADD(1)
                if (byte & 4u)   ROWADD(2)
                if (byte & 8u)   ROWADD(3)
                if (byte & 16u)  ROWADD(4)
                if (byte & 32u)  ROWADD(5)
                if (byte & 64u)  ROWADD(6)
                if (byte & 128u) ROWADD(7)
            }
        }

        // Eigen kc=320 panel boundary (320 = 40 tiles of 8; tail 128):
        // unfused fold into total, reset chain. Same k boundaries as R8.
        if (((kt + 1) % 40 == 0) || (kt == 255)) {
#pragma unroll
            for (int r = 0; r < 8; r++)
#pragma unroll
                for (int j = 0; j < 8; j++) {
                    tot[r][j] = __fadd_rn(tot[r][j], acc[r][j]);
                    acc[r][j] = 0.0f;
                }
        }

        __syncthreads();   // drains next-tile DMA (landed under compute)
        pkv = pknx;
        cur ^= 1;
    }

    // ---- Epilogue: 4 passes of 16 m-rows through Cl (Wl dead). ----
    // tot[r][j] is (m = m0g + 8w + r, h = h0 + 64j + lane).
    // Pass p covers waves 2p, 2p+1.
#pragma unroll
    for (int p = 0; p < 4; p++) {
        if ((w >> 1) == p) {
            const int mb = (w & 1) << 3;     // 0 or 8 within the pass tile
#pragma unroll
            for (int r = 0; r < 8; r++)
#pragma unroll
                for (int j = 0; j < 8; j++)
                    sh.Cl[mb + r][j * 64 + lane] = tot[r][j];
        }
        __syncthreads();
        // Store: per (s,instr), each 4-lane group writes one 64-B
        // contiguous segment of a Ct h-row (R10-proven clean pattern).
        const int mq = (tid & 3) << 2;
#pragma unroll
        for (int s = 0; s < 4; s++) {
            const int hr = (s << 7) + (tid >> 2);
            float4 v;
            v.x = sh.Cl[mq + 0][hr];
            v.y = sh.Cl[mq + 1][hr];
            v.z = sh.Cl[mq + 2][hr];
            v.w = sh.Cl[mq + 3][hr];
            *(float4*)&Ct[(size_t)(h0 + hr) * 8192 + m0g + (p << 4) + mq] = v;
        }
        if (p < 3) __syncthreads();
    }
#undef ROWADD
}

// One wave (64 lanes) per h; lane = batch b. Scan state f32, unfused.
// Batch-mean via ballot/popcount (exact). Validated numerics — UNCHANGED
// (verbatim R1 version; Wt layout [Hc][B][T] = [Hc][8192]).
__global__ __launch_bounds__(256) void scan_kernel(
    const float* __restrict__ Wt,          // [Hc][B][T] f32 chunk-local
    const float* __restrict__ threshold,   // [H] f32 global
    const float* __restrict__ p_tau_mem,
    const float* __restrict__ p_tau_syn,
    const float* __restrict__ p_target,
    const float* __restrict__ p_lr,
    float* __restrict__ out,               // [B][H][T] f32 global
    int h_base)
{
    __shared__ float S[4 * 64 * 17];
    __shared__ unsigned int Bits[4][64][4];

    const int tid  = threadIdx.x;
    const int w    = tid >> 6;
    const int lane = tid & 63;            // batch b
    const int hl   = blockIdx.x * 4 + w;  // chunk-local h

    const float tau_mem = p_tau_mem[0];
    const float tau_syn = p_tau_syn[0];
    const float target  = p_target[0];
    const float lr      = p_lr[0];
    const float a_mem = (float)exp((double)__fdiv_rn(-0.001f, tau_mem));
    const float a_syn = (float)exp((double)__fdiv_rn(-0.001f, tau_syn));

    float i_syn = 0.0f, v_mem = 0.0f;
    float thr = threshold[h_base + hl];
    float fre = 0.0f;
    unsigned int bits[4] = {0u, 0u, 0u, 0u};

    const int st4 = tid & 3;
    const int sb  = (tid >> 2) & 63;

    for (int tc = 0; tc < 128; tc += 16) {
        __syncthreads();
#pragma unroll
        for (int hh = 0; hh < 4; hh++) {
            const int hg = blockIdx.x * 4 + hh;
            float4 v = *(const float4*)&Wt[(size_t)hg * 8192 + sb * 128 + tc + 4 * st4];
            float* row = &S[(hh * 64 + sb) * 17];
            row[4 * st4 + 0] = v.x;
            row[4 * st4 + 1] = v.y;
            row[4 * st4 + 2] = v.z;
            row[4 * st4 + 3] = v.w;
        }
        __syncthreads();

        const float* row = &S[(w * 64 + lane) * 17];
#pragma unroll
        for (int tt = 0; tt < 16; tt++) {
            const int t = tc + tt;
            const float wv = row[tt];
            i_syn = __fadd_rn(__fmul_rn(a_syn, i_syn), wv);
            v_mem = __fadd_rn(__fmul_rn(a_mem, v_mem), i_syn);
            const bool sp = (v_mem >= thr);
            const unsigned long long mask = __ballot(sp);
            if (sp) v_mem = __fsub_rn(v_mem, thr);
            const int cnt = __popcll(mask);
            const float rate = __fmul_rn((float)cnt, 0.015625f);
            fre = __fadd_rn(__fmul_rn(0.99f, fre), __fmul_rn(0.01f, rate));
            thr = __fadd_rn(thr, __fmul_rn(lr, __fsub_rn(fre, target)));
            if (sp) bits[t >> 5] |= (1u << (t & 31));
        }
    }

    __syncthreads();
    Bits[w][lane][0] = bits[0];
    Bits[w][lane][1] = bits[1];
    Bits[w][lane][2] = bits[2];
    Bits[w][lane][3] = bits[3];
    __syncthreads();

    for (int b = 0; b < 64; b++) {
        const unsigned int word = Bits[w][b][lane >> 4];
        float2 v;
        v.x = ((word >> ((2 * lane) & 31)) & 1u) ? 1.0f : 0.0f;
        v.y = ((word >> ((2 * lane + 1) & 31)) & 1u) ? 1.0f : 0.0f;
        *(float2*)&out[((size_t)b * 2048 + h_base + hl) * 128 + 2 * lane] = v;
    }
}

extern "C" void kernel_launch(void* const* d_in, const int* in_sizes, int n_in,
                              void* d_out, int out_size, void* d_ws, size_t ws_size,
                              hipStream_t stream) {
    const float* spikes    = (const float*)d_in[0];
    const float* weight    = (const float*)d_in[1];
    const float* strength  = (const float*)d_in[2];
    const float* threshold = (const float*)d_in[3];
    const float* tau_mem   = (const float*)d_in[4];
    const float* tau_syn   = (const float*)d_in[5];
    const float* target    = (const float*)d_in[6];
    const float* lr        = (const float*)d_in[7];

    float* out = (float*)d_out;

    // ws: Wt [Hc][8192] f32 + weff [2048][Hc] f32 + bitsT 2 MiB.
    int Hc = 2048;
    while (Hc > 512 && (size_t)Hc * 40960ull + 2097152ull > ws_size) Hc >>= 1;

    float* Wt   = (float*)d_ws;
    float* weff = (float*)d_ws + (size_t)Hc * 8192;
    unsigned char* bitsT = (unsigned char*)(weff + (size_t)2048 * Hc);

    bits_kernel<<<32768, 256, 0, stream>>>(spikes, bitsT);

    for (int hb = 0; hb < 2048; hb += Hc) {
        weff_kernel<<<2048, 256, 0, stream>>>(weight, strength, weff, hb, Hc);
        gemm_kernel<<<dim3(Hc / 512, 128), 512, 0, stream>>>(weff, bitsT, Wt, Hc);
        scan_kernel<<<Hc / 4, 256, 0, stream>>>(
            Wt, threshold, tau_mem, tau_syn, target, lr, out, hb);
    }
}